// Round 2
// baseline (479.589 us; speedup 1.0000x reference)
//
#include <hip/hip_runtime.h>
#include <hip/hip_bf16.h>

#define NT   8
#define INF  128
#define OUTF 64

typedef __attribute__((ext_vector_type(8))) short short8;   // 8 bf16 (4 VGPRs) — MFMA A/B frag
typedef __attribute__((ext_vector_type(4))) float f32x4;    // MFMA C/D frag

__device__ __forceinline__ short f2bf(float f) {
  __hip_bfloat16 h = __float2bfloat16(f);
  return __builtin_bit_cast(short, h);
}

// ---------------------------------------------------------------------------
// d_ws layout: wbf[128 * 512] shorts (128 KB) — W pre-converted to bf16 and
// pre-swizzled into MFMA B-fragment order:
//   group fi = ((t*4 + s)*4 + nb), lane(q,c), j:
//   wbf[fi*512 + lane*8 + j] = bf16( W[t][s*32 + q*8 + j][nb*16 + c] )
// so the main kernel's B-frag load is one coalesced dwordx4 per lane.
// ---------------------------------------------------------------------------
__global__ void hl_wconv(const float* __restrict__ W, short* __restrict__ wbf) {
  const int tid   = blockIdx.x * blockDim.x + threadIdx.x;  // 0..8191
  const int combo = tid >> 6;                               // 0..127
  const int lane  = tid & 63;
  const int t = combo >> 4, s = (combo >> 2) & 3, nb = combo & 3;
  const int q = lane >> 4, c = lane & 15;
  const float* Wt = W + t * INF * OUTF;
  short8 v;
  #pragma unroll
  for (int j = 0; j < 8; ++j)
    v[j] = f2bf(Wt[(s * 32 + q * 8 + j) * OUTF + nb * 16 + c]);
  *(short8*)(wbf + (size_t)tid * 8) = v;
}

// ---------------------------------------------------------------------------
// Streaming masked-multi-type GEMM: each wave owns 16 CONSECUTIVE rows.
// acc = sum_t maskedA_t @ B_t  (A rows zeroed where type != t), bias in
// epilogue. No sort, no atomics, no LDS, no __syncthreads.
// Fragment mappings are the round-1-verified 16x16x32 ones:
//   A: m = lane&15, k = q*8 + j (per s-step of 32)
//   B: k = s*32 + q*8 + j, n = nb*16 + c
//   C/D: col = lane&15, row = q*4 + reg
// ---------------------------------------------------------------------------
__global__ __launch_bounds__(256) void hl_main(
    const float* __restrict__ x, const int* __restrict__ nty,
    const short* __restrict__ wbf, const float* __restrict__ b,
    float* __restrict__ out, int N) {
  const int ntiles = (N + 15) >> 4;
  const int wave = threadIdx.x >> 6;
  const int lane = threadIdx.x & 63;
  const int q = lane >> 4, c = lane & 15;
  const int nwaves = gridDim.x * 4;
  const short* wp = wbf + (size_t)lane * 8;   // + fi*512 per fragment group

  for (int tile = blockIdx.x * 4 + wave; tile < ntiles; tile += nwaves) {
    const int base = tile * 16;
    int rowa = base + c; if (rowa > N - 1) rowa = N - 1;   // never fires (N%16==0)
    const int ty = nty[rowa];
    const float* xr = x + (size_t)rowa * INF;

    // A frags: 8 contiguous floats per (s, lane) -> 2 dwordx4, cvt to bf16
    short8 A[4];
    #pragma unroll
    for (int s = 0; s < 4; ++s) {
      f32x4 v0 = *(const f32x4*)(xr + s * 32 + q * 8);
      f32x4 v1 = *(const f32x4*)(xr + s * 32 + q * 8 + 4);
      short8 a;
      #pragma unroll
      for (int j = 0; j < 4; ++j) { a[j] = f2bf(v0[j]); a[j + 4] = f2bf(v1[j]); }
      A[s] = a;
    }

    f32x4 acc[4] = {{0,0,0,0},{0,0,0,0},{0,0,0,0},{0,0,0,0}};
    const short8 z8 = {0,0,0,0,0,0,0,0};

    // B-frag stream with ping-pong prefetch (groups of 4 frags = 4 dwordx4).
    short8 BA[4], BB[4];
    #pragma unroll
    for (int nb = 0; nb < 4; ++nb) BA[nb] = *(const short8*)(wp + (size_t)nb * 512);

    #pragma unroll 1
    for (int t = 0; t < NT; ++t) {
      const int f0 = t * 16;
      const int fn = (f0 + 16 < 128) ? f0 + 16 : 124;  // clamped tail prefetch
      // s = 0: compute BA, prefetch -> BB
      #pragma unroll
      for (int nb = 0; nb < 4; ++nb) BB[nb] = *(const short8*)(wp + (size_t)(f0 + 4 + nb) * 512);
      { short8 am = (ty == t) ? A[0] : z8;
        #pragma unroll
        for (int nb = 0; nb < 4; ++nb)
          acc[nb] = __builtin_amdgcn_mfma_f32_16x16x32_bf16(am, BA[nb], acc[nb], 0, 0, 0); }
      // s = 1: compute BB, prefetch -> BA
      #pragma unroll
      for (int nb = 0; nb < 4; ++nb) BA[nb] = *(const short8*)(wp + (size_t)(f0 + 8 + nb) * 512);
      { short8 am = (ty == t) ? A[1] : z8;
        #pragma unroll
        for (int nb = 0; nb < 4; ++nb)
          acc[nb] = __builtin_amdgcn_mfma_f32_16x16x32_bf16(am, BB[nb], acc[nb], 0, 0, 0); }
      // s = 2: compute BA, prefetch -> BB
      #pragma unroll
      for (int nb = 0; nb < 4; ++nb) BB[nb] = *(const short8*)(wp + (size_t)(f0 + 12 + nb) * 512);
      { short8 am = (ty == t) ? A[2] : z8;
        #pragma unroll
        for (int nb = 0; nb < 4; ++nb)
          acc[nb] = __builtin_amdgcn_mfma_f32_16x16x32_bf16(am, BA[nb], acc[nb], 0, 0, 0); }
      // s = 3: compute BB, prefetch next type's group -> BA
      #pragma unroll
      for (int nb = 0; nb < 4; ++nb) BA[nb] = *(const short8*)(wp + (size_t)(fn + nb) * 512);
      { short8 am = (ty == t) ? A[3] : z8;
        #pragma unroll
        for (int nb = 0; nb < 4; ++nb)
          acc[nb] = __builtin_amdgcn_mfma_f32_16x16x32_bf16(am, BB[nb], acc[nb], 0, 0, 0); }
    }

    // Epilogue: rows base + q*4 + r; bias of each row's own type.
    const int rbase = base + q * 4;
    int4 tyv;
    if (rbase + 3 < N) {
      tyv = *(const int4*)(nty + rbase);           // rbase % 4 == 0, aligned
    } else {
      int t0 = rbase + 0 < N ? nty[rbase + 0] : 0;
      int t1 = rbase + 1 < N ? nty[rbase + 1] : 0;
      int t2 = rbase + 2 < N ? nty[rbase + 2] : 0;
      int t3 = rbase + 3 < N ? nty[rbase + 3] : 0;
      tyv.x = t0; tyv.y = t1; tyv.z = t2; tyv.w = t3;
    }
    const int trs[4] = {tyv.x, tyv.y, tyv.z, tyv.w};
    #pragma unroll
    for (int r = 0; r < 4; ++r) {
      const int row = rbase + r;
      if (row < N) {
        const float* br = b + trs[r] * OUTF + c;   // 2 KB table, L1-hot
        float* orow = out + (size_t)row * OUTF + c;
        #pragma unroll
        for (int nb = 0; nb < 4; ++nb)
          orow[nb * 16] = acc[nb][r] + br[nb * 16];
      }
    }
  }
}

extern "C" void kernel_launch(void* const* d_in, const int* in_sizes, int n_in,
                              void* d_out, int out_size, void* d_ws, size_t ws_size,
                              hipStream_t stream) {
  const float* x  = (const float*)d_in[0];
  const int*   nt = (const int*)d_in[1];
  const float* W  = (const float*)d_in[2];
  const float* b  = (const float*)d_in[3];
  float* out = (float*)d_out;
  const int N = in_sizes[1];
  short* wbf = (short*)d_ws;

  hl_wconv<<<32, 256, 0, stream>>>(W, wbf);
  hl_main<<<2048, 256, 0, stream>>>(x, nt, wbf, b, out, N);
}

// Round 3
// 428.683 us; speedup vs baseline: 1.1188x; 1.1188x over previous
//
#include <hip/hip_runtime.h>
#include <hip/hip_bf16.h>

#define NT   8
#define INF  128
#define OUTF 64
#define MT   4      // row-tiles per wave-pass (64 rows)

typedef __attribute__((ext_vector_type(8))) short short8;   // 8 bf16 (4 VGPRs)
typedef __attribute__((ext_vector_type(4))) float f32x4;

__device__ __forceinline__ short f2bf(float f) {
  __hip_bfloat16 h = __float2bfloat16(f);
  return __builtin_bit_cast(short, h);
}

// ---------------------------------------------------------------------------
// wbf[128 * 512] shorts (128 KB) in d_ws: W as bf16 in MFMA B-fragment order.
//   group g = (t*4 + s), frag fi = g*4 + nb, lane(q,c), j:
//   wbf[fi*512 + lane*8 + j] = bf16( W[t][s*32 + q*8 + j][nb*16 + c] )
// ---------------------------------------------------------------------------
__global__ void hl_wconv(const float* __restrict__ W, short* __restrict__ wbf) {
  const int tid   = blockIdx.x * blockDim.x + threadIdx.x;  // 0..8191
  const int combo = tid >> 6;                               // 0..127
  const int lane  = tid & 63;
  const int t = combo >> 4, s = (combo >> 2) & 3, nb = combo & 3;
  const int q = lane >> 4, c = lane & 15;
  const float* Wt = W + t * INF * OUTF;
  short8 v;
  #pragma unroll
  for (int j = 0; j < 8; ++j)
    v[j] = f2bf(Wt[(s * 32 + q * 8 + j) * OUTF + nb * 16 + c]);
  *(short8*)(wbf + (size_t)tid * 8) = v;
}

// ---------------------------------------------------------------------------
// Masked multi-type GEMM, M-blocked: each wave-pass owns 64 consecutive rows
// (4 tiles of 16). B-fragment groups stream from L2 ONCE per 64 rows (4x less
// L2 traffic than per-16), each group feeding 16 MFMAs. Per-row type masking
// zeroes A rows (A row m = lane&15) — exact sum over types, bias in epilogue.
// Fragment mappings (verified rounds 1-2):
//   A: m = lane&15, k = q*8 + j (per s-step of 32)
//   B: k = s*32 + q*8 + j, n = nb*16 + c
//   C/D: col = lane&15, row = q*4 + reg
// ---------------------------------------------------------------------------
__global__ __launch_bounds__(256, 2) void hl_main(
    const float* __restrict__ x, const int* __restrict__ nty,
    const short* __restrict__ wbf, const float* __restrict__ b,
    float* __restrict__ out, int N) {
  const int npass = (N + 63) >> 6;
  const int wave = threadIdx.x >> 6;
  const int lane = threadIdx.x & 63;
  const int q = lane >> 4, c = lane & 15;
  const int nwaves = gridDim.x * 4;
  const short* wp = wbf + (size_t)lane * 8;   // + fi*512 per fragment

  for (int pass = blockIdx.x * 4 + wave; pass < npass; pass += nwaves) {
    const int base = pass * 64;

    // ---- load A frags + per-row types for 4 tiles ----
    short8 A[MT][4];
    int tys[MT];
    #pragma unroll
    for (int i = 0; i < MT; ++i) {
      int rowa = base + i * 16 + c;
      if (rowa > N - 1) rowa = N - 1;          // tail clamp (loads stay valid)
      tys[i] = nty[rowa];
      const float* xr = x + (size_t)rowa * INF;
      #pragma unroll
      for (int s = 0; s < 4; ++s) {
        f32x4 v0 = *(const f32x4*)(xr + s * 32 + q * 8);
        f32x4 v1 = *(const f32x4*)(xr + s * 32 + q * 8 + 4);
        short8 a;
        #pragma unroll
        for (int j = 0; j < 4; ++j) { a[j] = f2bf(v0[j]); a[j + 4] = f2bf(v1[j]); }
        A[i][s] = a;
      }
    }

    f32x4 acc[MT][4];
    #pragma unroll
    for (int i = 0; i < MT; ++i)
      #pragma unroll
      for (int nb = 0; nb < 4; ++nb) acc[i][nb] = (f32x4){0, 0, 0, 0};

    const short8 z8 = {0, 0, 0, 0, 0, 0, 0, 0};

    // ---- B stream: 32 groups (t*4+s) of 4 frags, ping-pong prefetch ----
    short8 BA[4], BB[4];
    #pragma unroll
    for (int nb = 0; nb < 4; ++nb) BA[nb] = *(const short8*)(wp + (size_t)nb * 512);

    #pragma unroll 1
    for (int t = 0; t < NT; ++t) {
      #pragma unroll
      for (int s = 0; s < 4; ++s) {
        const int g = t * 4 + s;
        const int gn = (g + 1 < 32) ? g + 1 : 31;          // next group (clamped)
        if ((s & 1) == 0) {
          #pragma unroll
          for (int nb = 0; nb < 4; ++nb)
            BB[nb] = *(const short8*)(wp + (size_t)(gn * 4 + nb) * 512);
          #pragma unroll
          for (int i = 0; i < MT; ++i) {
            short8 am = (tys[i] == t) ? A[i][s] : z8;
            #pragma unroll
            for (int nb = 0; nb < 4; ++nb)
              acc[i][nb] = __builtin_amdgcn_mfma_f32_16x16x32_bf16(am, BA[nb], acc[i][nb], 0, 0, 0);
          }
        } else {
          #pragma unroll
          for (int nb = 0; nb < 4; ++nb)
            BA[nb] = *(const short8*)(wp + (size_t)(gn * 4 + nb) * 512);
          #pragma unroll
          for (int i = 0; i < MT; ++i) {
            short8 am = (tys[i] == t) ? A[i][s] : z8;
            #pragma unroll
            for (int nb = 0; nb < 4; ++nb)
              acc[i][nb] = __builtin_amdgcn_mfma_f32_16x16x32_bf16(am, BB[nb], acc[i][nb], 0, 0, 0);
          }
        }
      }
    }

    // ---- epilogue: rows tbase + q*4 + r, bias of each row's own type ----
    #pragma unroll
    for (int i = 0; i < MT; ++i) {
      const int rbase = base + i * 16 + q * 4;
      if (rbase >= N) continue;
      int4 tyv;
      if (rbase + 3 < N) {
        tyv = *(const int4*)(nty + rbase);
      } else {
        tyv.x = rbase + 0 < N ? nty[rbase + 0] : 0;
        tyv.y = rbase + 1 < N ? nty[rbase + 1] : 0;
        tyv.z = rbase + 2 < N ? nty[rbase + 2] : 0;
        tyv.w = rbase + 3 < N ? nty[rbase + 3] : 0;
      }
      const int trs[4] = {tyv.x, tyv.y, tyv.z, tyv.w};
      #pragma unroll
      for (int r = 0; r < 4; ++r) {
        const int row = rbase + r;
        if (row < N) {
          const float* br = b + trs[r] * OUTF + c;   // 2 KB table, L1-hot
          float* orow = out + (size_t)row * OUTF + c;
          #pragma unroll
          for (int nb = 0; nb < 4; ++nb)
            orow[nb * 16] = acc[i][nb][r] + br[nb * 16];
        }
      }
    }
  }
}

extern "C" void kernel_launch(void* const* d_in, const int* in_sizes, int n_in,
                              void* d_out, int out_size, void* d_ws, size_t ws_size,
                              hipStream_t stream) {
  const float* x  = (const float*)d_in[0];
  const int*   nt = (const int*)d_in[1];
  const float* W  = (const float*)d_in[2];
  const float* b  = (const float*)d_in[3];
  float* out = (float*)d_out;
  const int N = in_sizes[1];
  short* wbf = (short*)d_ws;

  hl_wconv<<<32, 256, 0, stream>>>(W, wbf);
  hl_main<<<512, 256, 0, stream>>>(x, nt, wbf, b, out, N);
}